// Round 10
// baseline (32.011 us; speedup 1.0000x reference)
//
#include <hip/hip_runtime.h>

// HungarianMatcher cost matrix:
//   C[n,m] = (1 - sigmoid(cls_boxes[n, cls_targets[m]-1]))      // class cost
//          + sum_k |pred_boxes[n,k] - tgt_boxes[m,k]|           // L1 box cost
//          - IoU(pred_boxes[n], tgt_boxes[m])                   // neg IoU cost
//
// N=16384, M=2048, NCLS=40. Output 128 MiB fp32 -> WRITE-PATH bound.
// History: 4 kernels (varied VALU count 22->15, LDS layout, store order,
// occupancy) all land 31-33 us = ~4.6 TB/s effective vs 6.4 TB/s fill rate.
// ROUND 10 = round 9 with ONE change: nontemporal final stores (isolated
// A/B; R4's NT test was confounded with other changes on the old scattered
// layout). Mechanism: 128 MiB write-once surface streaming through 32 MiB
// aggregate L2 -> write-allocate+evict churn; nt bypasses L2 residency.
// Neutral result => declare size-dependent write floor (roofline).
//
// Structure: block = 512 threads x 4 cols = full 2048-col row, NITER=16
// consecutive rows -> one contiguous 128 KB slab per block, ascending
// store order. Grid 1024 blocks = 4/CU, 32 waves/CU (VGPR 32).
// Math: l1 = 2*(u+v) + P + T (P baked into LDS sigmoid table, T in regs,
// u/v reuse IoU min/max); union eps-clamp dropped (>=1e-4); v_rcp_f32.

#define NPRED  16384
#define NTGT   2048
#define NCLS   40
#define NITER  16          // consecutive n-rows per block
#define RG     2           // rows per unrolled group (ds_read_b64)
#define BLOCK  512         // 512 threads x 4 cols = full row
#define SSTRIDE 20         // floats per class row in ST (16 rows + pad)

typedef float f32x4 __attribute__((ext_vector_type(4)));
typedef float f32x2 __attribute__((ext_vector_type(2)));

__global__ __launch_bounds__(BLOCK, 8) void matcher_cost_kernel(
    const float*  __restrict__ cls_boxes,    // [NPRED, NCLS]
    const int*    __restrict__ cls_targets,  // [NTGT]
    const float4* __restrict__ pred_boxes,   // [NPRED]
    const float4* __restrict__ tgt_boxes,    // [NTGT]
    float* __restrict__ out)                 // [NPRED, NTGT]
{
    __shared__ __align__(16) float ST[NCLS * SSTRIDE];   // 3.2 KB

    const int n0 = blockIdx.x * NITER;

    // ST[c][r] = 1/(1+exp(cls[n0+r][c])) + P[r],  P = pred (w+h) of row r.
    for (int e = threadIdx.x; e < NCLS * NITER; e += BLOCK) {
        int c = e >> 4;            // 0..39 (NITER == 16)
        int r = e & (NITER - 1);   // 0..15
        float4 pb = pred_boxes[n0 + r];                  // L1-hot, 16 rows
        float P = (pb.z - pb.x) + (pb.w - pb.y);
        float x = cls_boxes[(size_t)(n0 + r) * NCLS + c];
        ST[c * SSTRIDE + r] = __builtin_amdgcn_rcpf(1.0f + __expf(x)) + P;
    }

    // Register-cache this thread's 4 consecutive targets.
    const int mbase = threadIdx.x * 4;               // 0..2044
    float4 tb[4];
    float  area2[4], T[4];
    const float* stp[4];
    #pragma unroll
    for (int j = 0; j < 4; ++j) {
        tb[j] = tgt_boxes[mbase + j];
        float tw = tb[j].z - tb[j].x;
        float th = tb[j].w - tb[j].y;
        area2[j] = tw * th;
        T[j]     = tw + th;
        stp[j]   = &ST[(cls_targets[mbase + j] - 1) * SSTRIDE]; // labels 1..N
    }

    __syncthreads();

    float* orow = out + (size_t)n0 * NTGT + mbase;

    #pragma unroll
    for (int g = 0; g < NITER / RG; ++g) {
        // class(+P) costs for this thread's 4 classes, RG rows
        float sv[4][RG];
        #pragma unroll
        for (int j = 0; j < 4; ++j) {
            f32x2 s2 = *reinterpret_cast<const f32x2*>(stp[j] + g * RG);
            sv[j][0] = s2.x; sv[j][1] = s2.y;
        }

        #pragma unroll
        for (int k = 0; k < RG; ++k) {
            const int r = g * RG + k;
            float4 pb = pred_boxes[n0 + r];          // block-uniform -> SGPR
            float area1 = (pb.z - pb.x) * (pb.w - pb.y);

            f32x4 res;
            #pragma unroll
            for (int j = 0; j < 4; ++j) {
                float lx = fmaxf(pb.x, tb[j].x);
                float ly = fmaxf(pb.y, tb[j].y);
                float rx = fminf(pb.z, tb[j].z);
                float ry = fminf(pb.w, tb[j].w);
                float u  = lx - rx;
                float v  = ly - ry;
                float w  = fmaxf(-u, 0.0f);          // neg modifier, free
                float h  = fmaxf(-v, 0.0f);
                float ov = w * h;
                float uni = (area1 + area2[j]) - ov; // >= 1e-4, eps moot
                float rc  = __builtin_amdgcn_rcpf(uni);
                float base = fmaf(2.0f, u + v, sv[j][k] + T[j]); // cls + L1
                res[j] = fmaf(-ov, rc, base);                    // - IoU
            }
            __builtin_nontemporal_store(res,
                reinterpret_cast<f32x4*>(orow + (size_t)r * NTGT));
        }
    }
}

extern "C" void kernel_launch(void* const* d_in, const int* in_sizes, int n_in,
                              void* d_out, int out_size, void* d_ws, size_t ws_size,
                              hipStream_t stream) {
    const float*  cls_boxes   = (const float*)d_in[0];
    const int*    cls_targets = (const int*)d_in[1];
    const float4* pred_boxes  = (const float4*)d_in[2];
    const float4* tgt_boxes   = (const float4*)d_in[3];
    float* out = (float*)d_out;

    const int grid = NPRED / NITER;   // 1024 blocks, contiguous 128 KB slabs
    matcher_cost_kernel<<<grid, BLOCK, 0, stream>>>(
        cls_boxes, cls_targets, pred_boxes, tgt_boxes, out);
}

// Round 11
// 31.270 us; speedup vs baseline: 1.0237x; 1.0237x over previous
//
#include <hip/hip_runtime.h>

// HungarianMatcher cost matrix:
//   C[n,m] = (1 - sigmoid(cls_boxes[n, cls_targets[m]-1]))      // class cost
//          + sum_k |pred_boxes[n,k] - tgt_boxes[m,k]|           // L1 box cost
//          - IoU(pred_boxes[n], tgt_boxes[m])                   // neg IoU cost
//
// N=16384, M=2048, NCLS=40. Output 128 MiB fp32 -> WRITE-PATH bound.
// FINAL KERNEL (= round-9 best variant, NT store reverted after isolated
// A/B showed it neutral-to-negative).
//
// Roofline evidence: five structurally diverse kernels (VALU 22->15 ops,
// LDS transpose, occupancy 4->8 waves/SIMD, scattered->contiguous slabs,
// NT vs cached stores) all land 31-33 us. Counters: WRITE_SIZE = ideal
// 137 MB, FETCH_SIZE = 4.3 MB, VALUBusy ~3%. Model t = OH + bytes/BW with
// OH ~12 us (dispatch/ramp/drain, kernel-invariant) and BW ~7.6 TB/s fits
// both this kernel (30.6 us predicted) and the harness's 512 MiB fills
// (82.7 us predicted, 78-87 measured). Size-dependent write floor reached.
//
// Structure: block = 512 threads x 4 cols = full 2048-col row, NITER=16
// consecutive rows -> one contiguous 128 KB slab per block, ascending
// store order. Grid 1024 blocks = 4/CU, 32 waves/CU (VGPR 32).
// Math: l1 = 2*(u+v) + P + T (P baked into LDS sigmoid table, T in regs,
// u/v reuse IoU min/max); union eps-clamp dropped (>=1e-4); v_rcp_f32.

#define NPRED  16384
#define NTGT   2048
#define NCLS   40
#define NITER  16          // consecutive n-rows per block
#define RG     2           // rows per unrolled group (ds_read_b64)
#define BLOCK  512         // 512 threads x 4 cols = full row
#define SSTRIDE 20         // floats per class row in ST (16 rows + pad)

typedef float f32x4 __attribute__((ext_vector_type(4)));
typedef float f32x2 __attribute__((ext_vector_type(2)));

__global__ __launch_bounds__(BLOCK, 8) void matcher_cost_kernel(
    const float*  __restrict__ cls_boxes,    // [NPRED, NCLS]
    const int*    __restrict__ cls_targets,  // [NTGT]
    const float4* __restrict__ pred_boxes,   // [NPRED]
    const float4* __restrict__ tgt_boxes,    // [NTGT]
    float* __restrict__ out)                 // [NPRED, NTGT]
{
    __shared__ __align__(16) float ST[NCLS * SSTRIDE];   // 3.2 KB

    const int n0 = blockIdx.x * NITER;

    // ST[c][r] = 1/(1+exp(cls[n0+r][c])) + P[r],  P = pred (w+h) of row r.
    for (int e = threadIdx.x; e < NCLS * NITER; e += BLOCK) {
        int c = e >> 4;            // 0..39 (NITER == 16)
        int r = e & (NITER - 1);   // 0..15
        float4 pb = pred_boxes[n0 + r];                  // L1-hot, 16 rows
        float P = (pb.z - pb.x) + (pb.w - pb.y);
        float x = cls_boxes[(size_t)(n0 + r) * NCLS + c];
        ST[c * SSTRIDE + r] = __builtin_amdgcn_rcpf(1.0f + __expf(x)) + P;
    }

    // Register-cache this thread's 4 consecutive targets.
    const int mbase = threadIdx.x * 4;               // 0..2044
    float4 tb[4];
    float  area2[4], T[4];
    const float* stp[4];
    #pragma unroll
    for (int j = 0; j < 4; ++j) {
        tb[j] = tgt_boxes[mbase + j];
        float tw = tb[j].z - tb[j].x;
        float th = tb[j].w - tb[j].y;
        area2[j] = tw * th;
        T[j]     = tw + th;
        stp[j]   = &ST[(cls_targets[mbase + j] - 1) * SSTRIDE]; // labels 1..N
    }

    __syncthreads();

    float* orow = out + (size_t)n0 * NTGT + mbase;

    #pragma unroll
    for (int g = 0; g < NITER / RG; ++g) {
        // class(+P) costs for this thread's 4 classes, RG rows
        float sv[4][RG];
        #pragma unroll
        for (int j = 0; j < 4; ++j) {
            f32x2 s2 = *reinterpret_cast<const f32x2*>(stp[j] + g * RG);
            sv[j][0] = s2.x; sv[j][1] = s2.y;
        }

        #pragma unroll
        for (int k = 0; k < RG; ++k) {
            const int r = g * RG + k;
            float4 pb = pred_boxes[n0 + r];          // block-uniform -> SGPR
            float area1 = (pb.z - pb.x) * (pb.w - pb.y);

            f32x4 res;
            #pragma unroll
            for (int j = 0; j < 4; ++j) {
                float lx = fmaxf(pb.x, tb[j].x);
                float ly = fmaxf(pb.y, tb[j].y);
                float rx = fminf(pb.z, tb[j].z);
                float ry = fminf(pb.w, tb[j].w);
                float u  = lx - rx;
                float v  = ly - ry;
                float w  = fmaxf(-u, 0.0f);          // neg modifier, free
                float h  = fmaxf(-v, 0.0f);
                float ov = w * h;
                float uni = (area1 + area2[j]) - ov; // >= 1e-4, eps moot
                float rc  = __builtin_amdgcn_rcpf(uni);
                float base = fmaf(2.0f, u + v, sv[j][k] + T[j]); // cls + L1
                res[j] = fmaf(-ov, rc, base);                    // - IoU
            }
            *reinterpret_cast<f32x4*>(orow + (size_t)r * NTGT) = res;
        }
    }
}

extern "C" void kernel_launch(void* const* d_in, const int* in_sizes, int n_in,
                              void* d_out, int out_size, void* d_ws, size_t ws_size,
                              hipStream_t stream) {
    const float*  cls_boxes   = (const float*)d_in[0];
    const int*    cls_targets = (const int*)d_in[1];
    const float4* pred_boxes  = (const float4*)d_in[2];
    const float4* tgt_boxes   = (const float4*)d_in[3];
    float* out = (float*)d_out;

    const int grid = NPRED / NITER;   // 1024 blocks, contiguous 128 KB slabs
    matcher_cost_kernel<<<grid, BLOCK, 0, stream>>>(
        cls_boxes, cls_targets, pred_boxes, tgt_boxes, out);
}